// Round 1
// baseline (218.162 us; speedup 1.0000x reference)
//
#include <hip/hip_runtime.h>
#include <math.h>

#define H 1024
#define S 32768

// ---------------------------------------------------------------------------
// Stage 1: partial matvec  v[h] = sum_o W[o,h] * hidden[o]
// 64 blocks x 256 threads. Block b handles o in [b*16, b*16+16).
// Thread t handles columns h = 4t..4t+3 (float4, coalesced across the wave).
// ---------------------------------------------------------------------------
__global__ void matvec_partial_kernel(const float* __restrict__ W,
                                      const float* __restrict__ hidden,
                                      float* __restrict__ vpart) {
    const int t = threadIdx.x;      // 0..255
    const int b = blockIdx.x;       // 0..63
    const int h4 = t * 4;
    float4 acc = make_float4(0.f, 0.f, 0.f, 0.f);
    const int o0 = b * 16;
#pragma unroll
    for (int i = 0; i < 16; ++i) {
        const int o = o0 + i;
        const float hv = hidden[o];  // block-uniform -> scalar load
        const float4 w = *reinterpret_cast<const float4*>(&W[(size_t)o * H + h4]);
        acc.x += hv * w.x;
        acc.y += hv * w.y;
        acc.z += hv * w.z;
        acc.w += hv * w.w;
    }
    *reinterpret_cast<float4*>(&vpart[(size_t)b * H + h4]) = acc;
}

// ---------------------------------------------------------------------------
// Stage 2: reduce 64 partials -> v[1024].  1 block x 256 threads, float4 each.
// ---------------------------------------------------------------------------
__global__ void matvec_reduce_kernel(const float* __restrict__ vpart,
                                     float* __restrict__ v) {
    const int t = threadIdx.x;
    const int h4 = t * 4;
    float4 acc = make_float4(0.f, 0.f, 0.f, 0.f);
#pragma unroll 8
    for (int b = 0; b < 64; ++b) {
        const float4 p = *reinterpret_cast<const float4*>(&vpart[(size_t)b * H + h4]);
        acc.x += p.x;
        acc.y += p.y;
        acc.z += p.z;
        acc.w += p.w;
    }
    *reinterpret_cast<float4*>(&v[h4]) = acc;
}

// ---------------------------------------------------------------------------
// Stage 3: energies[s] = enc[s,:] . v   (the 128 MB read — must be coalesced)
// One wave (64 lanes) per row; 256-thread block = 4 waves = 4 rows; 8192 blocks.
// Lane i reads float4 at column j*256 + i*4  (wave reads 1 KiB per instr).
// ---------------------------------------------------------------------------
__global__ void energies_kernel(const float* __restrict__ enc,
                                const float* __restrict__ v,
                                float* __restrict__ energies) {
    const int wave = threadIdx.x >> 6;   // 0..3
    const int lane = threadIdx.x & 63;
    const int s = blockIdx.x * 4 + wave;
    const float* row = enc + (size_t)s * H;
    float acc = 0.f;
#pragma unroll
    for (int j = 0; j < 4; ++j) {
        const int idx = j * 256 + lane * 4;
        const float4 e  = *reinterpret_cast<const float4*>(&row[idx]);
        const float4 vv = *reinterpret_cast<const float4*>(&v[idx]);
        acc += e.x * vv.x + e.y * vv.y + e.z * vv.z + e.w * vv.w;
    }
    // 64-lane shuffle reduction
#pragma unroll
    for (int off = 32; off > 0; off >>= 1)
        acc += __shfl_down(acc, off, 64);
    if (lane == 0) energies[s] = acc;
}

// ---------------------------------------------------------------------------
// Stage 4: softmax over 32768 energies. Single block, 1024 threads (16 waves).
// Two passes (max, then sum-of-exp) with LDS cross-wave reduction.
// ---------------------------------------------------------------------------
__global__ void softmax_kernel(const float* __restrict__ energies,
                               float* __restrict__ out) {
    __shared__ float red[16];
    const int t = threadIdx.x;
    const int lane = t & 63;
    const int wid = t >> 6;

    // ---- pass 1: max ----
    float m = -INFINITY;
    for (int i = t; i < S; i += 1024) m = fmaxf(m, energies[i]);
#pragma unroll
    for (int off = 32; off > 0; off >>= 1)
        m = fmaxf(m, __shfl_down(m, off, 64));
    if (lane == 0) red[wid] = m;
    __syncthreads();
    if (t < 16) {
        float mm = red[t];
#pragma unroll
        for (int off = 8; off > 0; off >>= 1)
            mm = fmaxf(mm, __shfl_down(mm, off, 16));
        if (t == 0) red[0] = mm;
    }
    __syncthreads();
    m = red[0];
    __syncthreads();  // everyone has read red[0] before it is overwritten

    // ---- pass 2: sum of exp ----
    float ssum = 0.f;
    for (int i = t; i < S; i += 1024) ssum += __expf(energies[i] - m);
#pragma unroll
    for (int off = 32; off > 0; off >>= 1)
        ssum += __shfl_down(ssum, off, 64);
    if (lane == 0) red[wid] = ssum;
    __syncthreads();
    if (t < 16) {
        float sm = red[t];
#pragma unroll
        for (int off = 8; off > 0; off >>= 1)
            sm += __shfl_down(sm, off, 16);
        if (t == 0) red[0] = sm;
    }
    __syncthreads();
    const float inv = 1.0f / red[0];

    // ---- write normalized probabilities ----
    for (int i = t; i < S; i += 1024)
        out[i] = __expf(energies[i] - m) * inv;
}

// ---------------------------------------------------------------------------
// Launch
// ---------------------------------------------------------------------------
extern "C" void kernel_launch(void* const* d_in, const int* in_sizes, int n_in,
                              void* d_out, int out_size, void* d_ws, size_t ws_size,
                              hipStream_t stream) {
    const float* hidden = (const float*)d_in[0];   // [1024]
    const float* enc    = (const float*)d_in[1];   // [32768, 1024]
    const float* W      = (const float*)d_in[2];   // [1024, 1024]
    // d_in[3] = b: b.hidden is constant across s -> cancels in softmax; unused.
    float* out = (float*)d_out;                    // [32768]

    // workspace layout (floats): [0,65536) vpart, [65536,66560) v, [66560,99328) energies
    float* vpart    = (float*)d_ws;
    float* v        = vpart + 64 * H;
    float* energies = v + H;

    matvec_partial_kernel<<<64, 256, 0, stream>>>(W, hidden, vpart);
    matvec_reduce_kernel<<<1, 256, 0, stream>>>(vpart, v);
    energies_kernel<<<S / 4, 256, 0, stream>>>(enc, v, energies);
    softmax_kernel<<<1, 1024, 0, stream>>>(energies, out);
}

// Round 2
// 211.644 us; speedup vs baseline: 1.0308x; 1.0308x over previous
//
#include <hip/hip_runtime.h>
#include <math.h>

#define H 1024
#define S 32768

// ---------------------------------------------------------------------------
// Stage 1: partial matvec  v[h] = sum_o W[o,h] * hidden[o]
// 64 blocks x 256 threads. Block b handles o in [b*16, b*16+16).
// Thread t handles columns h = 4t..4t+3 (float4, coalesced).
// ---------------------------------------------------------------------------
__global__ void matvec_partial_kernel(const float* __restrict__ W,
                                      const float* __restrict__ hidden,
                                      float* __restrict__ vpart) {
    const int t = threadIdx.x;
    const int b = blockIdx.x;
    const int h4 = t * 4;
    float4 acc = make_float4(0.f, 0.f, 0.f, 0.f);
    const int o0 = b * 16;
#pragma unroll
    for (int i = 0; i < 16; ++i) {
        const int o = o0 + i;
        const float hv = hidden[o];
        const float4 w = *reinterpret_cast<const float4*>(&W[(size_t)o * H + h4]);
        acc.x += hv * w.x;
        acc.y += hv * w.y;
        acc.z += hv * w.z;
        acc.w += hv * w.w;
    }
    *reinterpret_cast<float4*>(&vpart[(size_t)b * H + h4]) = acc;
}

// ---------------------------------------------------------------------------
// Stage 2: reduce 64 partials -> v[1024].  1 block x 256 threads.
// ---------------------------------------------------------------------------
__global__ void matvec_reduce_kernel(const float* __restrict__ vpart,
                                     float* __restrict__ v) {
    const int t = threadIdx.x;
    const int h4 = t * 4;
    float4 acc = make_float4(0.f, 0.f, 0.f, 0.f);
#pragma unroll 8
    for (int b = 0; b < 64; ++b) {
        const float4 p = *reinterpret_cast<const float4*>(&vpart[(size_t)b * H + h4]);
        acc.x += p.x;
        acc.y += p.y;
        acc.z += p.z;
        acc.w += p.w;
    }
    *reinterpret_cast<float4*>(&v[h4]) = acc;
}

// ---------------------------------------------------------------------------
// Stage 3: energies + per-block online-softmax partials.
// 2048 blocks x 256 threads = 4 waves/block; each wave computes 4 rows.
// v stripe loaded ONCE per wave into registers and reused across rows.
// Emits energies[S] plus per-block (m_b, s_b) online-softmax partials.
// ---------------------------------------------------------------------------
__global__ void energies_kernel(const float* __restrict__ enc,
                                const float* __restrict__ v,
                                float* __restrict__ energies,
                                float* __restrict__ mpart,
                                float* __restrict__ spart) {
    const int wave = threadIdx.x >> 6;
    const int lane = threadIdx.x & 63;
    const int gwave = blockIdx.x * 4 + wave;   // 0..8191
    const int s0 = gwave * 4;                  // 4 rows per wave

    float4 vv[4];
#pragma unroll
    for (int j = 0; j < 4; ++j)
        vv[j] = *reinterpret_cast<const float4*>(&v[j * 256 + lane * 4]);

    float e[4];
#pragma unroll
    for (int r = 0; r < 4; ++r) {
        const float* row = enc + (size_t)(s0 + r) * H;
        float acc = 0.f;
#pragma unroll
        for (int j = 0; j < 4; ++j) {
            const float4 ev = *reinterpret_cast<const float4*>(&row[j * 256 + lane * 4]);
            acc += ev.x * vv[j].x + ev.y * vv[j].y + ev.z * vv[j].z + ev.w * vv[j].w;
        }
        // butterfly: every lane ends with the full row sum
#pragma unroll
        for (int off = 32; off > 0; off >>= 1)
            acc += __shfl_xor(acc, off, 64);
        e[r] = acc;
    }

    if (lane == 0) {
        energies[s0 + 0] = e[0];
        energies[s0 + 1] = e[1];
        energies[s0 + 2] = e[2];
        energies[s0 + 3] = e[3];
    }

    // per-wave online softmax partial
    const float mw = fmaxf(fmaxf(e[0], e[1]), fmaxf(e[2], e[3]));
    const float sw = __expf(e[0] - mw) + __expf(e[1] - mw) +
                     __expf(e[2] - mw) + __expf(e[3] - mw);

    __shared__ float lm[4], ls[4];
    if (lane == 0) { lm[wave] = mw; ls[wave] = sw; }
    __syncthreads();
    if (threadIdx.x == 0) {
        const float m = fmaxf(fmaxf(lm[0], lm[1]), fmaxf(lm[2], lm[3]));
        const float s = ls[0] * __expf(lm[0] - m) + ls[1] * __expf(lm[1] - m) +
                        ls[2] * __expf(lm[2] - m) + ls[3] * __expf(lm[3] - m);
        mpart[blockIdx.x] = m;
        spart[blockIdx.x] = s;
    }
}

// ---------------------------------------------------------------------------
// Stage 4: finalize. 1 block x 1024 threads. Reduce 2048 (m,s) partials ->
// global (m, sum); write out[i] = exp(e_i - m) / sum.
// ---------------------------------------------------------------------------
__global__ void finalize_kernel(const float* __restrict__ energies,
                                const float* __restrict__ mpart,
                                const float* __restrict__ spart,
                                float* __restrict__ out) {
    __shared__ float red[16];
    __shared__ float gm_s, gs_s;
    const int t = threadIdx.x;
    const int lane = t & 63;
    const int wid = t >> 6;

    // global max over 2048 block maxes (2 per thread)
    float m = fmaxf(mpart[t], mpart[t + 1024]);
#pragma unroll
    for (int off = 32; off > 0; off >>= 1)
        m = fmaxf(m, __shfl_xor(m, off, 64));
    if (lane == 0) red[wid] = m;
    __syncthreads();
    if (t == 0) {
        float mm = red[0];
#pragma unroll
        for (int i = 1; i < 16; ++i) mm = fmaxf(mm, red[i]);
        gm_s = mm;
    }
    __syncthreads();
    const float gm = gm_s;

    // global sum with rescale
    float s = spart[t] * __expf(mpart[t] - gm) +
              spart[t + 1024] * __expf(mpart[t + 1024] - gm);
#pragma unroll
    for (int off = 32; off > 0; off >>= 1)
        s += __shfl_xor(s, off, 64);
    __syncthreads();   // red[] reuse safety
    if (lane == 0) red[wid] = s;
    __syncthreads();
    if (t == 0) {
        float ss = 0.f;
#pragma unroll
        for (int i = 0; i < 16; ++i) ss += red[i];
        gs_s = ss;
    }
    __syncthreads();
    const float inv = 1.0f / gs_s;

#pragma unroll
    for (int k = 0; k < S / 1024; ++k)
        out[t + k * 1024] = __expf(energies[t + k * 1024] - gm) * inv;
}

// ---------------------------------------------------------------------------
// Launch
// ---------------------------------------------------------------------------
extern "C" void kernel_launch(void* const* d_in, const int* in_sizes, int n_in,
                              void* d_out, int out_size, void* d_ws, size_t ws_size,
                              hipStream_t stream) {
    const float* hidden = (const float*)d_in[0];   // [1024]
    const float* enc    = (const float*)d_in[1];   // [32768, 1024]
    const float* W      = (const float*)d_in[2];   // [1024, 1024]
    // d_in[3] = b: (b . hidden) is constant across s -> cancels in softmax.
    float* out = (float*)d_out;                    // [32768]

    float* vpart    = (float*)d_ws;        // 64*1024
    float* v        = vpart + 64 * H;      // 1024
    float* energies = v + H;               // 32768
    float* mpart    = energies + S;        // 2048
    float* spart    = mpart + 2048;        // 2048

    matvec_partial_kernel<<<64, 256, 0, stream>>>(W, hidden, vpart);
    matvec_reduce_kernel<<<1, 256, 0, stream>>>(vpart, v);
    energies_kernel<<<2048, 256, 0, stream>>>(enc, v, energies, mpart, spart);
    finalize_kernel<<<1, 1024, 0, stream>>>(energies, mpart, spart, out);
}